// Round 20
// baseline (329.738 us; speedup 1.0000x reference)
//
#include <hip/hip_runtime.h>
#include <stdint.h>

typedef unsigned short u16;
typedef __attribute__((ext_vector_type(4))) float f32x4;
typedef __attribute__((ext_vector_type(8))) short bf16x8;
typedef __attribute__((ext_vector_type(8))) u16 u16x8;

#define T_SEQ  2048
#define EMB    2048
#define HD     128
#define NHEAD  16
#define NE3    6144
#define SCALE  0.29730177875068026f   // 128^-0.25
#define LOG2E  1.44269504088896f

typedef __attribute__((address_space(3))) char* lds_t;
typedef const __attribute__((address_space(1))) char* gl_t;

__device__ __forceinline__ void gld16(const void* g, void* l) {
  __builtin_amdgcn_global_load_lds((gl_t)g, (lds_t)l, 16, 0, 0);
}

__device__ __forceinline__ u16 f2bf(float f) {
  union { float f; uint32_t u; } c; c.f = f;
  uint32_t r = c.u + 0x7fffu + ((c.u >> 16) & 1u);
  return (u16)(r >> 16);
}

// ---------------- fp32 -> bf16 conversion (memory-bound) ----------------
__global__ __launch_bounds__(256) void cvt_bf16(const float* __restrict__ in,
                                                u16* __restrict__ out, int n8) {
  int i = blockIdx.x * 256 + threadIdx.x;
  if (i >= n8) return;
  const float4* p = (const float4*)in + (size_t)i * 2;
  float4 a = p[0], b = p[1];
  u16x8 o;
  o[0]=f2bf(a.x); o[1]=f2bf(a.y); o[2]=f2bf(a.z); o[3]=f2bf(a.w);
  o[4]=f2bf(b.x); o[5]=f2bf(b.y); o[6]=f2bf(b.z); o[7]=f2bf(b.w);
  *((u16x8*)out + i) = o;
}

// shared helpers: 64B-row slabs with involution col' = c ^ ((row>>1)&3)
__device__ __forceinline__ bf16x8 rdfrag(const char* slot, int row, int lq) {
  return *(const bf16x8*)(slot + row*64 + ((lq ^ ((row >> 1) & 3)) << 4));
}
__device__ __forceinline__ void stg512(const char* g, int K2, int kbyte,
                                       char* slot, int j, int tid) {
  int lb = j*8192 + tid*16;
  int row = lb >> 6, c = (lb >> 4) & 3;
  gld16(g + (size_t)row*K2 + kbyte + ((c ^ ((row >> 1) & 3)) << 4), slot + lb);
}

// ======== QKV GEMM: 256x256 tile, R12 pipeline, serial frag reads ========
// Staged-volume reduction: per-output staged bytes halve vs 128x256 (total
// 1.15GB -> 0.77GB).  R14 ablation: serial ds_read is FREE (hidden under
// staging) -> single frag set (af[8]+bf[4] = 48 VGPR), acc[8][4] -> AGPRs
// (R13 proved no spill at this shape).  4 bufs x 32KB = 128KB, depth-3
// staging, uniform vmcnt(8) gate.  Ledger (L=4 loads/tile): prologue
// t0,t1,t2 = 12 out; ITER(t): vmcnt(8) completes tile t exactly; barrier;
// STAGE(t+3) into BUF((t+3)&3) [holds t-1; every wave's t-1 reads done at
// its ITER(t-1) lgkmcnt(0), ordered before this stage by ITER(t)'s barrier];
// read t's 12 frags; lgkmcnt(0); 32 MFMA.  Tail restages identical bytes.
// Grid 16x24=384; supertile regionId=i>>4, s=i&15: bM=(regionId%4)*4+(s>>2),
// bN=(regionId/4)*4+(s&3) — bijective, 4x4 region per XCD chunk.
__global__ __launch_bounds__(512, 2) void gemmQ(
    const u16* __restrict__ A, const u16* __restrict__ Bm, int K,
    const float* __restrict__ cosT, const float* __restrict__ sinT,
    const float* __restrict__ bias,
    u16* __restrict__ Qh, u16* __restrict__ Kh, u16* __restrict__ Vt)
{
  __shared__ __align__(16) char lds[131072];  // 4 bufs x (A 16KB + B 16KB)
  const int tid = threadIdx.x;
  const int lane = tid & 63, w = tid >> 6;
  const int wm = w >> 2, wn = w & 3;          // 2M x 4N waves, wave 128x64
  const int l15 = lane & 15, lq = lane >> 4;

  const int i = blockIdx.x;
  const int regionId = i >> 4, s = i & 15;
  const int bM = (regionId % 4) * 4 + (s >> 2);
  const int bN = (regionId / 4) * 4 + (s & 3);

  const char* Ag = (const char*)(A + (size_t)bM * 256 * K);
  const char* Bg = (const char*)(Bm + (size_t)bN * 256 * K);
  const int K2 = K * 2;
  const int nT = K >> 5;                      // 64 tiles of BK=32

  #define BUF(k) (lds + ((k) & 3) * 32768)
  #define STAGE(t) do { int kb_ = (t) << 6; char* b_ = BUF(t);        \
    stg512(Ag, K2, kb_, b_, 0, tid);                                  \
    stg512(Ag, K2, kb_, b_, 1, tid);                                  \
    stg512(Bg, K2, kb_, b_ + 16384, 0, tid);                          \
    stg512(Bg, K2, kb_, b_ + 16384, 1, tid); } while (0)

  STAGE(0); STAGE(1); STAGE(2);               // 12 in flight

  f32x4 acc[8][4] = {};

  for (int t = 0; t < nT; ++t) {
    asm volatile("s_waitcnt vmcnt(8)" ::: "memory");   // tile t landed
    __builtin_amdgcn_s_barrier();
    __builtin_amdgcn_sched_barrier(0);

    const int ts = (t + 3 < nT) ? t + 3 : nT - 1;      // tail: identical bytes
    STAGE(ts);

    const char* rb = BUF(t);
    bf16x8 af[8], bf[4];
    #pragma unroll
    for (int j = 0; j < 8; j++) af[j] = rdfrag(rb, wm*128 + j*16 + l15, lq);
    #pragma unroll
    for (int j = 0; j < 4; j++) bf[j] = rdfrag(rb + 16384, wn*64 + j*16 + l15, lq);
    asm volatile("s_waitcnt lgkmcnt(0)" ::: "memory");
    __builtin_amdgcn_sched_barrier(0);
    __builtin_amdgcn_s_setprio(1);
    #pragma unroll
    for (int mi = 0; mi < 8; mi++)
      #pragma unroll
      for (int ni = 0; ni < 4; ni++)
        acc[mi][ni] = __builtin_amdgcn_mfma_f32_16x16x32_bf16(af[mi], bf[ni], acc[mi][ni], 0, 0, 0);
    __builtin_amdgcn_s_setprio(0);
  }
  asm volatile("s_waitcnt vmcnt(0)" ::: "memory");
  #undef STAGE
  #undef BUF

  // epilogue: +bias, RoPE (angle row = n % T), scatter Qh/Kh [bh][t][d],
  // Vt [bh][d][t].  cbase%128 in {0,64} -> block-uniform seg/head.
  const int cbase = bN*256 + wn*64;
  const int seg  = cbase >> 11;
  const int head = (cbase >> 7) & 15;
  #pragma unroll
  for (int mi = 0; mi < 8; mi++) {
    #pragma unroll
    for (int ni = 0; ni < 4; ni++) {
      int col = cbase + ni*16 + l15;
      int d = col & 127;
      float bi = bias[col];
      f32x4 v = acc[mi][ni];
      #pragma unroll
      for (int rr = 0; rr < 4; rr++) {
        int n = bM*256 + wm*128 + mi*16 + lq*4 + rr;   // flat token = t*B+b
        float val = v[rr] + bi;
        int t = n >> 1, b = n & 1;
        int bh = b*NHEAD + head;
        if (seg == 1) {
          Vt[((size_t)bh*HD + d)*T_SEQ + t] = f2bf(val);
        } else {
          float par = __shfl_xor(val, 1);
          int fidx = d >> 1;
          float cs = cosT[(n & (T_SEQ-1))*64 + fidx];
          float sn = sinT[(n & (T_SEQ-1))*64 + fidx];
          val = (d & 1) ? (par*sn + val*cs) : (val*cs - par*sn);
          val *= SCALE;
          u16* dst = (seg == 0) ? Kh : Qh;
          dst[((size_t)bh*T_SEQ + t)*HD + d] = f2bf(val);
        }
      }
    }
  }
}

// ======== out-proj GEMM: R12 gemmF 128x256 exact (proven ~40us) ========
__global__ __launch_bounds__(512, 2) void gemmO(
    const u16* __restrict__ A, const u16* __restrict__ Bm, int K, int N,
    float* __restrict__ Cout)
{
  __shared__ __align__(16) char lds[98304];   // 4 bufs x (A 8KB + B 16KB)
  const int tid = threadIdx.x;
  const int lane = tid & 63, w = tid >> 6;
  const int wm = w >> 2, wn = w & 3;
  const int l15 = lane & 15, lq = lane >> 4;

  const int i = blockIdx.x;
  const int r = i >> 8, x = i & 7, s = (i >> 3) & 31;
  const int regionId = r*8 + x;
  const int bM = (regionId & 3)*8 + (s >> 2);
  const int bN = (regionId >> 2)*4 + (s & 3);

  const char* Ag = (const char*)(A + (size_t)bM * 128 * K);
  const char* Bg = (const char*)(Bm + (size_t)bN * 256 * K);
  const int K2 = K * 2;
  const int nT = K >> 5;

  #define BUF(k) (lds + ((k) & 3) * 24576)
  #define STAGE(t) do { int kb_ = (t) << 6; char* b_ = BUF(t);        \
    stg512(Ag, K2, kb_, b_, 0, tid);                                  \
    stg512(Bg, K2, kb_, b_ + 8192, 0, tid);                           \
    stg512(Bg, K2, kb_, b_ + 8192, 1, tid); } while (0)

  STAGE(0); STAGE(1); STAGE(2);
  asm volatile("s_waitcnt vmcnt(6)" ::: "memory");
  __builtin_amdgcn_s_barrier();
  __builtin_amdgcn_sched_barrier(0);

  bf16x8 afA[4], bfA[4], afB[4], bfB[4];
  #pragma unroll
  for (int j = 0; j < 4; j++) afA[j] = rdfrag(BUF(0), wm*64 + j*16 + l15, lq);
  #pragma unroll
  for (int j = 0; j < 4; j++) bfA[j] = rdfrag(BUF(0) + 8192, wn*64 + j*16 + l15, lq);

  f32x4 acc[4][4] = {};

  #define ITER(t, CA, CB, OA, OB) do {                                     \
    asm volatile("s_waitcnt vmcnt(3)" ::: "memory");                       \
    __builtin_amdgcn_s_barrier();                                          \
    __builtin_amdgcn_sched_barrier(0);                                     \
    const int tr_ = ((t) + 1 < nT) ? (t) + 1 : nT - 1;                     \
    const char* rb_ = BUF(tr_);                                            \
    _Pragma("unroll")                                                      \
    for (int j_ = 0; j_ < 4; j_++) OA[j_] = rdfrag(rb_, wm*64 + j_*16 + l15, lq); \
    _Pragma("unroll")                                                      \
    for (int j_ = 0; j_ < 4; j_++) OB[j_] = rdfrag(rb_ + 8192, wn*64 + j_*16 + l15, lq); \
    asm volatile("s_waitcnt lgkmcnt(8)" ::: "memory");                     \
    __builtin_amdgcn_sched_barrier(0);                                     \
    const int ts_ = ((t) + 3 < nT) ? (t) + 3 : nT - 1;                     \
    STAGE(ts_);                                                            \
    __builtin_amdgcn_s_setprio(1);                                         \
    _Pragma("unroll")                                                      \
    for (int mi_ = 0; mi_ < 4; mi_++)                                      \
      _Pragma("unroll")                                                    \
      for (int ni_ = 0; ni_ < 4; ni_++)                                    \
        acc[mi_][ni_] = __builtin_amdgcn_mfma_f32_16x16x32_bf16(CA[mi_], CB[ni_], acc[mi_][ni_], 0, 0, 0); \
    __builtin_amdgcn_s_setprio(0);                                         \
  } while (0)

  for (int t = 0; t < nT; t += 2) {
    ITER(t,     afA, bfA, afB, bfB);
    ITER(t + 1, afB, bfB, afA, bfA);
  }
  asm volatile("s_waitcnt vmcnt(0) lgkmcnt(0)" ::: "memory");
  __builtin_amdgcn_sched_barrier(0);
  #undef ITER
  #undef STAGE
  #undef BUF

  #pragma unroll
  for (int mi = 0; mi < 4; mi++) {
    int row = bM*128 + wm*64 + mi*16 + lq*4;
    #pragma unroll
    for (int ni = 0; ni < 4; ni++) {
      int col = bN*256 + wn*64 + ni*16 + l15;
      #pragma unroll
      for (int rr = 0; rr < 4; rr++)
        Cout[(size_t)(row + rr) * N + col] = acc[mi][ni][rr];
    }
  }
}

// ---------------- causal flash attention, bf16 MFMA (R19 exact) ----------
#define PSW(row) ((((row) & 7) << 4) ^ (((row) & 8) << 2))

__global__ __launch_bounds__(512, 4) void attn_fwd(
    const u16* __restrict__ Qh, const u16* __restrict__ Kh,
    const u16* __restrict__ Vt, u16* __restrict__ O)
{
  const int i = blockIdx.x;
  const int kk = i >> 8, c = i & 255;
  const int b5 = c & 15;
  const int qb = kk ? (15 - b5) : b5;
  const int bh = (c >> 4) + kk * 16;

  const int tid = threadIdx.x, lane = tid & 63, w = tid >> 6;
  const int l15 = lane & 15, lq = lane >> 4;

  __shared__ u16 Ks[2][64*128];
  __shared__ u16 Vs[2][128*64];
  __shared__ char Ps[8][2048];

  const int q0 = qb*128 + w*16;
  bf16x8 qf[4];
  #pragma unroll
  for (int dc = 0; dc < 4; dc++)
    qf[dc] = *(const bf16x8*)(Qh + ((size_t)bh*T_SEQ + q0 + l15)*HD + dc*32 + lq*8);

  const int nkb = 2*qb + 2;

  #define STAGE_KV(t, b) do {                                              \
    _Pragma("unroll")                                                      \
    for (int j_ = 0; j_ < 2; j_++) {                                       \
      int lb_ = tid*16 + j_*8192;                                          \
      int row_ = lb_ >> 8, bir_ = lb_ & 255;                               \
      int sb_ = bir_ ^ ((row_ & 7) << 4);                                  \
      gld16((const char*)Kh + (((size_t)bh*T_SEQ + (t)*64 + row_) << 8) + sb_, \
            (char*)Ks[b] + lb_);                                           \
    }                                                                      \
    _Pragma("unroll")                                                      \
    for (int j_ = 0; j_ < 2; j_++) {                                       \
      int lb_ = tid*16 + j_*8192;                                          \
      int row_ = lb_ >> 7, bir_ = lb_ & 127;                               \
      int sb_ = bir_ ^ ((row_ & 7) << 4);                                  \
      gld16((const char*)Vt + ((size_t)(bh*HD + row_)*T_SEQ)*2 + (t)*128 + sb_, \
            (char*)Vs[b] + lb_);                                           \
    }                                                                      \
  } while (0)

  STAGE_KV(0, 0);
  STAGE_KV(1, 1);

  f32x4 o[8] = {};
  float m[4], l_[4];
  #pragma unroll
  for (int r = 0; r < 4; r++) { m[r] = -1e30f; l_[r] = 0.f; }

  for (int kb = 0; kb < nkb; ++kb) {
    asm volatile("s_waitcnt vmcnt(4)" ::: "memory");
    __builtin_amdgcn_s_barrier();
    __builtin_amdgcn_sched_barrier(0);

    const char* Kb = (const char*)Ks[kb & 1];
    const char* Vb = (const char*)Vs[kb & 1];

    f32x4 sacc[4];
    #pragma unroll
    for (int nf = 0; nf < 4; nf++) {
      f32x4 z = {};
      sacc[nf] = z;
      #pragma unroll
      for (int dc = 0; dc < 4; dc++) {
        int row = nf*16 + l15;
        int bir = (dc*64 + lq*16) ^ ((row & 7) << 4);
        bf16x8 kf = *(const bf16x8*)(Kb + row*256 + bir);
        sacc[nf] = __builtin_amdgcn_mfma_f32_16x16x32_bf16(qf[dc], kf, sacc[nf], 0, 0, 0);
      }
    }

    if (kb*64 + 63 > q0) {
      #pragma unroll
      for (int nf = 0; nf < 4; nf++)
        #pragma unroll
        for (int r = 0; r < 4; r++) {
          int key = kb*64 + nf*16 + l15;
          int qr  = q0 + lq*4 + r;
          if (key > qr) sacc[nf][r] = -1e30f;
        }
    }

    #pragma unroll
    for (int r = 0; r < 4; r++) {
      float mx = fmaxf(fmaxf(sacc[0][r], sacc[1][r]), fmaxf(sacc[2][r], sacc[3][r]));
      mx = fmaxf(mx, __shfl_xor(mx, 1));
      mx = fmaxf(mx, __shfl_xor(mx, 2));
      mx = fmaxf(mx, __shfl_xor(mx, 4));
      mx = fmaxf(mx, __shfl_xor(mx, 8));
      float newm = fmaxf(m[r], mx);
      float sc = exp2f((m[r] - newm) * LOG2E);
      float s = 0.f;
      #pragma unroll
      for (int nf = 0; nf < 4; nf++) {
        float p = exp2f((sacc[nf][r] - newm) * LOG2E);
        sacc[nf][r] = p;
        s += p;
      }
      l_[r] = l_[r] * sc + s;
      m[r] = newm;
      #pragma unroll
      for (int nf = 0; nf < 8; nf++) o[nf][r] *= sc;
    }

    #pragma unroll
    for (int nf = 0; nf < 4; nf++)
      #pragma unroll
      for (int r = 0; r < 4; r++) {
        int prow = lq*4 + r;
        int pbyte = prow*128 + (((nf*16 + l15)*2) ^ PSW(prow));
        *(u16*)(Ps[w] + pbyte) = f2bf(sacc[nf][r]);
      }

    #pragma unroll
    for (int kc = 0; kc < 2; kc++) {
      int pb = (kc*64 + lq*16) ^ PSW(l15);
      bf16x8 pf = *(const bf16x8*)(Ps[w] + l15*128 + pb);
      #pragma unroll
      for (int nf = 0; nf < 8; nf++) {
        int row = nf*16 + l15;
        int bir = (kc*64 + lq*16) ^ ((row & 7) << 4);
        bf16x8 vf = *(const bf16x8*)(Vb + row*128 + bir);
        o[nf] = __builtin_amdgcn_mfma_f32_16x16x32_bf16(pf, vf, o[nf], 0, 0, 0);
      }
    }

    __builtin_amdgcn_s_barrier();
    const int tnext = (kb + 2 < nkb) ? kb + 2 : nkb - 1;
    STAGE_KV(tnext, kb & 1);
  }
  asm volatile("s_waitcnt vmcnt(0)" ::: "memory");
  #undef STAGE_KV

  const int b = bh >> 4, h = bh & 15;
  #pragma unroll
  for (int r = 0; r < 4; r++) {
    float l = l_[r];
    l += __shfl_xor(l, 1);
    l += __shfl_xor(l, 2);
    l += __shfl_xor(l, 4);
    l += __shfl_xor(l, 8);
    float inv = 1.0f / l;
    int t = q0 + lq*4 + r;
    size_t base = ((size_t)(t*2 + b))*EMB + h*HD;
    #pragma unroll
    for (int nf = 0; nf < 8; nf++)
      O[base + nf*16 + l15] = f2bf(o[nf][r] * inv);
  }
}

// ---------------- launch ----------------
extern "C" void kernel_launch(void* const* d_in, const int* in_sizes, int n_in,
                              void* d_out, int out_size, void* d_ws, size_t ws_size,
                              hipStream_t stream) {
  const float* query = (const float*)d_in[0];
  const float* Wqkv  = (const float*)d_in[1];
  const float* bqkv  = (const float*)d_in[2];
  const float* Wo    = (const float*)d_in[3];
  // d_in[4] = bo — reference does NOT add it
  const float* fcos  = (const float*)d_in[5];
  const float* fsin  = (const float*)d_in[6];
  float* out = (float*)d_out;
  char* ws = (char*)d_ws;

  // workspace layout (bytes), total 96MB
  u16* WQb = (u16*)(ws + 0);          // 6144x2048 bf16 = 25165824
  u16* WOb = (u16*)(ws + 25165824);   // 2048x2048 bf16 =  8388608
  u16* A1  = (u16*)(ws + 33554432);   // 4096x2048 bf16 (query; reused as attn out)
  u16* QH  = (u16*)(ws + 50331648);   // [32][2048][128] bf16
  u16* KH  = (u16*)(ws + 67108864);
  u16* VT  = (u16*)(ws + 83886080);   // [32][128][2048] bf16  (end: 100663296)

  cvt_bf16<<<4096, 256, 0, stream>>>(query, A1, 1048576);
  cvt_bf16<<<6144, 256, 0, stream>>>(Wqkv, WQb, 1572864);
  cvt_bf16<<<2048, 256, 0, stream>>>(Wo,   WOb,  524288);

  gemmQ<<<384, 512, 0, stream>>>(A1, WQb, 2048,
                                 fcos, fsin, bqkv, QH, KH, VT);

  attn_fwd<<<512, 512, 0, stream>>>(QH, KH, VT, A1);

  gemmO<<<256, 512, 0, stream>>>(A1, WOb, 2048, EMB, out);
}

// Round 21
// 306.341 us; speedup vs baseline: 1.0764x; 1.0764x over previous
//
#include <hip/hip_runtime.h>
#include <stdint.h>

typedef unsigned short u16;
typedef __attribute__((ext_vector_type(4))) float f32x4;
typedef __attribute__((ext_vector_type(8))) short bf16x8;
typedef __attribute__((ext_vector_type(8))) u16 u16x8;

#define T_SEQ  2048
#define EMB    2048
#define HD     128
#define NHEAD  16
#define NE3    6144
#define SCALE  0.29730177875068026f   // 128^-0.25
#define LOG2E  1.44269504088896f

typedef __attribute__((address_space(3))) char* lds_t;
typedef const __attribute__((address_space(1))) char* gl_t;

__device__ __forceinline__ void gld16(const void* g, void* l) {
  __builtin_amdgcn_global_load_lds((gl_t)g, (lds_t)l, 16, 0, 0);
}

__device__ __forceinline__ u16 f2bf(float f) {
  union { float f; uint32_t u; } c; c.f = f;
  uint32_t r = c.u + 0x7fffu + ((c.u >> 16) & 1u);
  return (u16)(r >> 16);
}

// ---------------- fused fp32 -> bf16 conversion (one dispatch) ----------
// Segments (in 8-elem chunks): query 1048576 | Wqkv 1572864 | Wo 524288.
// Grid-stride; saves 2 launches + inter-launch bubbles vs 3 kernels.
#define CVT_N1 1048576
#define CVT_N2 2621440              // N1 + 1572864
#define CVT_NT 3145728              // + 524288
__global__ __launch_bounds__(256) void cvt_all(
    const float* __restrict__ query, const float* __restrict__ Wqkv,
    const float* __restrict__ Wo, u16* __restrict__ oq,
    u16* __restrict__ owq, u16* __restrict__ owo) {
  for (int i = blockIdx.x * 256 + threadIdx.x; i < CVT_NT; i += 2048 * 256) {
    const float* src; u16* dst; int j;
    if (i < CVT_N1)      { src = query; dst = oq;  j = i; }
    else if (i < CVT_N2) { src = Wqkv;  dst = owq; j = i - CVT_N1; }
    else                 { src = Wo;    dst = owo; j = i - CVT_N2; }
    const float4* p = (const float4*)src + (size_t)j * 2;
    float4 a = p[0], b = p[1];
    u16x8 o;
    o[0]=f2bf(a.x); o[1]=f2bf(a.y); o[2]=f2bf(a.z); o[3]=f2bf(a.w);
    o[4]=f2bf(b.x); o[5]=f2bf(b.y); o[6]=f2bf(b.z); o[7]=f2bf(b.w);
    *((u16x8*)dst + j) = o;
  }
}

// shared helpers: 64B-row slabs with involution col' = c ^ ((row>>1)&3)
__device__ __forceinline__ bf16x8 rdfrag(const char* slot, int row, int lq) {
  return *(const bf16x8*)(slot + row*64 + ((lq ^ ((row >> 1) & 3)) << 4));
}
__device__ __forceinline__ void stg512(const char* g, int K2, int kbyte,
                                       char* slot, int j, int tid) {
  int lb = j*8192 + tid*16;
  int row = lb >> 6, c = (lb >> 4) & 3;
  gld16(g + (size_t)row*K2 + kbyte + ((c ^ ((row >> 1) & 3)) << 4), slot + lb);
}

// ======== 128x256 bf16 GEMM (R12/R19 exact — proven 150us QKV) ========
template<int EPI>
__global__ __launch_bounds__(512, 2) void gemmF(
    const u16* __restrict__ A, const u16* __restrict__ Bm, int K, int N,
    const float* __restrict__ cosT, const float* __restrict__ sinT,
    const float* __restrict__ bias,
    u16* __restrict__ Qh, u16* __restrict__ Kh, u16* __restrict__ Vt,
    float* __restrict__ Cout)
{
  __shared__ __align__(16) char lds[98304];   // 4 bufs x (A 8KB + B 16KB)
  const int tid = threadIdx.x;
  const int lane = tid & 63, w = tid >> 6;
  const int wm = w >> 2, wn = w & 3;          // 2M x 4N waves
  const int l15 = lane & 15, lq = lane >> 4;

  const int i = blockIdx.x;
  const int r = i >> 8, x = i & 7, s = (i >> 3) & 31;
  const int regionId = r*8 + x;
  const int bM = (regionId & 3)*8 + (s >> 2);
  const int bN = (regionId >> 2)*4 + (s & 3);

  const char* Ag = (const char*)(A + (size_t)bM * 128 * K);
  const char* Bg = (const char*)(Bm + (size_t)bN * 256 * K);
  const int K2 = K * 2;
  const int nT = K >> 5;                      // 64 (even)

  #define BUF(k) (lds + ((k) & 3) * 24576)
  #define STAGE(t) do { int kb_ = (t) << 6; char* b_ = BUF(t);        \
    stg512(Ag, K2, kb_, b_, 0, tid);                                  \
    stg512(Bg, K2, kb_, b_ + 8192, 0, tid);                           \
    stg512(Bg, K2, kb_, b_ + 8192, 1, tid); } while (0)

  STAGE(0); STAGE(1); STAGE(2);
  asm volatile("s_waitcnt vmcnt(6)" ::: "memory");   // t0 landed
  __builtin_amdgcn_s_barrier();
  __builtin_amdgcn_sched_barrier(0);

  bf16x8 afA[4], bfA[4], afB[4], bfB[4];
  #pragma unroll
  for (int j = 0; j < 4; j++) afA[j] = rdfrag(BUF(0), wm*64 + j*16 + l15, lq);
  #pragma unroll
  for (int j = 0; j < 4; j++) bfA[j] = rdfrag(BUF(0) + 8192, wn*64 + j*16 + l15, lq);

  f32x4 acc[4][4] = {};

  #define ITER(t, CA, CB, OA, OB) do {                                     \
    asm volatile("s_waitcnt vmcnt(3)" ::: "memory");  /* tile t+1 landed */\
    __builtin_amdgcn_s_barrier();                                          \
    __builtin_amdgcn_sched_barrier(0);                                     \
    const int tr_ = ((t) + 1 < nT) ? (t) + 1 : nT - 1;                     \
    const char* rb_ = BUF(tr_);                                            \
    _Pragma("unroll")                                                      \
    for (int j_ = 0; j_ < 4; j_++) OA[j_] = rdfrag(rb_, wm*64 + j_*16 + l15, lq); \
    _Pragma("unroll")                                                      \
    for (int j_ = 0; j_ < 4; j_++) OB[j_] = rdfrag(rb_ + 8192, wn*64 + j_*16 + l15, lq); \
    asm volatile("s_waitcnt lgkmcnt(8)" ::: "memory"); /* cur set ready */ \
    __builtin_amdgcn_sched_barrier(0);                                     \
    const int ts_ = ((t) + 3 < nT) ? (t) + 3 : nT - 1;                     \
    STAGE(ts_);                                                            \
    __builtin_amdgcn_s_setprio(1);                                         \
    _Pragma("unroll")                                                      \
    for (int mi_ = 0; mi_ < 4; mi_++)                                      \
      _Pragma("unroll")                                                    \
      for (int ni_ = 0; ni_ < 4; ni_++)                                    \
        acc[mi_][ni_] = __builtin_amdgcn_mfma_f32_16x16x32_bf16(CA[mi_], CB[ni_], acc[mi_][ni_], 0, 0, 0); \
    __builtin_amdgcn_s_setprio(0);                                         \
  } while (0)

  for (int t = 0; t < nT; t += 2) {
    ITER(t,     afA, bfA, afB, bfB);
    ITER(t + 1, afB, bfB, afA, bfA);
  }
  asm volatile("s_waitcnt vmcnt(0) lgkmcnt(0)" ::: "memory");
  __builtin_amdgcn_sched_barrier(0);
  #undef ITER
  #undef STAGE
  #undef BUF

  if (EPI == 0) {
    #pragma unroll
    for (int mi = 0; mi < 4; mi++) {
      int row = bM*128 + wm*64 + mi*16 + lq*4;
      #pragma unroll
      for (int ni = 0; ni < 4; ni++) {
        int col = bN*256 + wn*64 + ni*16 + l15;
        #pragma unroll
        for (int rr = 0; rr < 4; rr++)
          Cout[(size_t)(row + rr) * N + col] = acc[mi][ni][rr];
      }
    }
  } else {
    const int cbase = bN*256 + wn*64;
    const int seg  = cbase >> 11;
    const int head = (cbase >> 7) & 15;
    #pragma unroll
    for (int mi = 0; mi < 4; mi++) {
      #pragma unroll
      for (int ni = 0; ni < 4; ni++) {
        int col = cbase + ni*16 + l15;
        int d = col & 127;
        float bi = bias[col];
        f32x4 v = acc[mi][ni];
        #pragma unroll
        for (int rr = 0; rr < 4; rr++) {
          int n = bM*128 + wm*64 + mi*16 + lq*4 + rr;   // flat token = t*B+b
          float val = v[rr] + bi;
          int t = n >> 1, b = n & 1;
          int bh = b*NHEAD + head;
          if (seg == 1) {
            Vt[((size_t)bh*HD + d)*T_SEQ + t] = f2bf(val);
          } else {
            // RoPE: reference's flat reshape makes angle row = n % T
            float par = __shfl_xor(val, 1);
            int fidx = d >> 1;
            float cs = cosT[(n & (T_SEQ-1))*64 + fidx];
            float sn = sinT[(n & (T_SEQ-1))*64 + fidx];
            val = (d & 1) ? (par*sn + val*cs) : (val*cs - par*sn);
            val *= SCALE;
            u16* dst = (seg == 0) ? Kh : Qh;
            dst[((size_t)bh*T_SEQ + t)*HD + d] = f2bf(val);
          }
        }
      }
    }
  }
}

// ---------------- causal flash attention, bf16 MFMA (R19 exact) ----------
#define PSW(row) ((((row) & 7) << 4) ^ (((row) & 8) << 2))

__global__ __launch_bounds__(512, 4) void attn_fwd(
    const u16* __restrict__ Qh, const u16* __restrict__ Kh,
    const u16* __restrict__ Vt, u16* __restrict__ O)
{
  const int i = blockIdx.x;
  const int kk = i >> 8, c = i & 255;
  const int b5 = c & 15;
  const int qb = kk ? (15 - b5) : b5;
  const int bh = (c >> 4) + kk * 16;

  const int tid = threadIdx.x, lane = tid & 63, w = tid >> 6;
  const int l15 = lane & 15, lq = lane >> 4;

  __shared__ u16 Ks[2][64*128];
  __shared__ u16 Vs[2][128*64];
  __shared__ char Ps[8][2048];

  const int q0 = qb*128 + w*16;
  bf16x8 qf[4];
  #pragma unroll
  for (int dc = 0; dc < 4; dc++)
    qf[dc] = *(const bf16x8*)(Qh + ((size_t)bh*T_SEQ + q0 + l15)*HD + dc*32 + lq*8);

  const int nkb = 2*qb + 2;

  #define STAGE_KV(t, b) do {                                              \
    _Pragma("unroll")                                                      \
    for (int j_ = 0; j_ < 2; j_++) {                                       \
      int lb_ = tid*16 + j_*8192;                                          \
      int row_ = lb_ >> 8, bir_ = lb_ & 255;                               \
      int sb_ = bir_ ^ ((row_ & 7) << 4);                                  \
      gld16((const char*)Kh + (((size_t)bh*T_SEQ + (t)*64 + row_) << 8) + sb_, \
            (char*)Ks[b] + lb_);                                           \
    }                                                                      \
    _Pragma("unroll")                                                      \
    for (int j_ = 0; j_ < 2; j_++) {                                       \
      int lb_ = tid*16 + j_*8192;                                          \
      int row_ = lb_ >> 7, bir_ = lb_ & 127;                               \
      int sb_ = bir_ ^ ((row_ & 7) << 4);                                  \
      gld16((const char*)Vt + ((size_t)(bh*HD + row_)*T_SEQ)*2 + (t)*128 + sb_, \
            (char*)Vs[b] + lb_);                                           \
    }                                                                      \
  } while (0)

  STAGE_KV(0, 0);
  STAGE_KV(1, 1);

  f32x4 o[8] = {};
  float m[4], l_[4];
  #pragma unroll
  for (int r = 0; r < 4; r++) { m[r] = -1e30f; l_[r] = 0.f; }

  for (int kb = 0; kb < nkb; ++kb) {
    asm volatile("s_waitcnt vmcnt(4)" ::: "memory");
    __builtin_amdgcn_s_barrier();
    __builtin_amdgcn_sched_barrier(0);

    const char* Kb = (const char*)Ks[kb & 1];
    const char* Vb = (const char*)Vs[kb & 1];

    f32x4 sacc[4];
    #pragma unroll
    for (int nf = 0; nf < 4; nf++) {
      f32x4 z = {};
      sacc[nf] = z;
      #pragma unroll
      for (int dc = 0; dc < 4; dc++) {
        int row = nf*16 + l15;
        int bir = (dc*64 + lq*16) ^ ((row & 7) << 4);
        bf16x8 kf = *(const bf16x8*)(Kb + row*256 + bir);
        sacc[nf] = __builtin_amdgcn_mfma_f32_16x16x32_bf16(qf[dc], kf, sacc[nf], 0, 0, 0);
      }
    }

    if (kb*64 + 63 > q0) {   // near-diagonal: causal mask (wave-local)
      #pragma unroll
      for (int nf = 0; nf < 4; nf++)
        #pragma unroll
        for (int r = 0; r < 4; r++) {
          int key = kb*64 + nf*16 + l15;
          int qr  = q0 + lq*4 + r;
          if (key > qr) sacc[nf][r] = -1e30f;
        }
    }

    // online softmax; l_ stays per-lane (reduced once in epilogue)
    #pragma unroll
    for (int r = 0; r < 4; r++) {
      float mx = fmaxf(fmaxf(sacc[0][r], sacc[1][r]), fmaxf(sacc[2][r], sacc[3][r]));
      mx = fmaxf(mx, __shfl_xor(mx, 1));
      mx = fmaxf(mx, __shfl_xor(mx, 2));
      mx = fmaxf(mx, __shfl_xor(mx, 4));
      mx = fmaxf(mx, __shfl_xor(mx, 8));
      float newm = fmaxf(m[r], mx);
      float sc = exp2f((m[r] - newm) * LOG2E);
      float s = 0.f;
      #pragma unroll
      for (int nf = 0; nf < 4; nf++) {
        float p = exp2f((sacc[nf][r] - newm) * LOG2E);
        sacc[nf][r] = p;
        s += p;
      }
      l_[r] = l_[r] * sc + s;               // per-lane partial
      m[r] = newm;
      #pragma unroll
      for (int nf = 0; nf < 8; nf++) o[nf][r] *= sc;
    }

    // P -> bf16 tile in wave-private LDS slab (conflict-free involution)
    #pragma unroll
    for (int nf = 0; nf < 4; nf++)
      #pragma unroll
      for (int r = 0; r < 4; r++) {
        int prow = lq*4 + r;
        int pbyte = prow*128 + (((nf*16 + l15)*2) ^ PSW(prow));
        *(u16*)(Ps[w] + pbyte) = f2bf(sacc[nf][r]);
      }

    // O += P V
    #pragma unroll
    for (int kc = 0; kc < 2; kc++) {
      int pb = (kc*64 + lq*16) ^ PSW(l15);
      bf16x8 pf = *(const bf16x8*)(Ps[w] + l15*128 + pb);
      #pragma unroll
      for (int nf = 0; nf < 8; nf++) {
        int row = nf*16 + l15;
        int bir = (kc*64 + lq*16) ^ ((row & 7) << 4);
        bf16x8 vf = *(const bf16x8*)(Vb + row*128 + bir);
        o[nf] = __builtin_amdgcn_mfma_f32_16x16x32_bf16(pf, vf, o[nf], 0, 0, 0);
      }
    }

    __builtin_amdgcn_s_barrier();            // all waves done reading buf
    const int tnext = (kb + 2 < nkb) ? kb + 2 : nkb - 1;
    STAGE_KV(tnext, kb & 1);
  }
  asm volatile("s_waitcnt vmcnt(0)" ::: "memory");
  #undef STAGE_KV

  // epilogue: reduce l_ partials across the 16 row-lanes, then write O
  const int b = bh >> 4, h = bh & 15;
  #pragma unroll
  for (int r = 0; r < 4; r++) {
    float l = l_[r];
    l += __shfl_xor(l, 1);
    l += __shfl_xor(l, 2);
    l += __shfl_xor(l, 4);
    l += __shfl_xor(l, 8);
    float inv = 1.0f / l;
    int t = q0 + lq*4 + r;
    size_t base = ((size_t)(t*2 + b))*EMB + h*HD;
    #pragma unroll
    for (int nf = 0; nf < 8; nf++)
      O[base + nf*16 + l15] = f2bf(o[nf][r] * inv);
  }
}

// ---------------- launch ----------------
extern "C" void kernel_launch(void* const* d_in, const int* in_sizes, int n_in,
                              void* d_out, int out_size, void* d_ws, size_t ws_size,
                              hipStream_t stream) {
  const float* query = (const float*)d_in[0];
  const float* Wqkv  = (const float*)d_in[1];
  const float* bqkv  = (const float*)d_in[2];
  const float* Wo    = (const float*)d_in[3];
  // d_in[4] = bo — reference does NOT add it
  const float* fcos  = (const float*)d_in[5];
  const float* fsin  = (const float*)d_in[6];
  float* out = (float*)d_out;
  char* ws = (char*)d_ws;

  // workspace layout (bytes), total 96MB
  u16* WQb = (u16*)(ws + 0);          // 6144x2048 bf16 = 25165824
  u16* WOb = (u16*)(ws + 25165824);   // 2048x2048 bf16 =  8388608
  u16* A1  = (u16*)(ws + 33554432);   // 4096x2048 bf16 (query; reused as attn out)
  u16* QH  = (u16*)(ws + 50331648);   // [32][2048][128] bf16
  u16* KH  = (u16*)(ws + 67108864);
  u16* VT  = (u16*)(ws + 83886080);   // [32][128][2048] bf16  (end: 100663296)

  cvt_all<<<2048, 256, 0, stream>>>(query, Wqkv, Wo, A1, WQb, WOb);

  gemmF<1><<<768, 512, 0, stream>>>(A1, WQb, 2048, NE3,
                                    fcos, fsin, bqkv, QH, KH, VT, nullptr);

  attn_fwd<<<512, 512, 0, stream>>>(QH, KH, VT, A1);

  gemmF<0><<<256, 512, 0, stream>>>(A1, WOb, 2048, EMB,
                                    nullptr, nullptr, nullptr,
                                    nullptr, nullptr, nullptr, out);
}